// Round 5
// baseline (16967.755 us; speedup 1.0000x reference)
//
#include <hip/hip_runtime.h>
#include <stdint.h>

typedef __attribute__((ext_vector_type(8))) short short8;
typedef __attribute__((ext_vector_type(4))) float f32x4;
typedef __attribute__((ext_vector_type(4))) unsigned short u16x4;

// Problem constants: T=512, B=64, D=768, H=768, 4H=3072
#define NWG 96

// ws layout (bytes, all 256-aligned)
#define OFF_XBF   0UL
#define SZ_XBF    (512UL*64*768*2)
#define OFF_WXB   (OFF_XBF + SZ_XBF)
#define SZ_WB     (3072UL*768*2)
#define OFF_WHB   (OFF_WXB + SZ_WB)
#define OFF_BALL  (OFF_WHB + SZ_WB)
#define SZ_BALL   (3072UL*4)
#define OFF_XG    (OFF_BALL + SZ_BALL)
#define SZ_XG     (512UL*3072*64*2)
#define OFF_HBUF  (OFF_XG + SZ_XG)
#define SZ_HBUF   (2UL*64*768*2)
#define OFF_FLAGS (OFF_HBUF + SZ_HBUF)
#define SZ_FLAGS  (NWG*16UL*4)

__device__ __forceinline__ float bf2f(unsigned short u){
  union{unsigned int i; float f;} v; v.i = ((unsigned int)u)<<16; return v.f;
}
__device__ __forceinline__ unsigned short f2bf(float f){
  union{float f; unsigned int i;} v; v.f = f;
  unsigned int x = v.i;
  return (unsigned short)((x + 0x7fffu + ((x>>16)&1u)) >> 16);
}
__device__ __forceinline__ float sigm(float x){ return 1.0f/(1.0f + __expf(-x)); }
// overflow-safe tanh: large |x| -> exp -> inf -> r=1, copysign fixes sign
__device__ __forceinline__ float tanh_s(float x){
  float e = __expf(2.0f*fabsf(x));
  float r = 1.0f - 2.0f/(e+1.0f);
  return copysignf(r, x);
}
__device__ __forceinline__ f32x4 mfma16(short8 a, short8 b, f32x4 c){
  return __builtin_amdgcn_mfma_f32_16x16x32_bf16(a, b, c, 0, 0, 0);
}

// ---- converters ----
__global__ void k_conv_x(const float* __restrict__ x, unsigned short* __restrict__ xb, int n4){
  int i = blockIdx.x*blockDim.x + threadIdx.x;
  if (i >= n4) return;
  float4 v = ((const float4*)x)[i];
  u16x4 o = { f2bf(v.x), f2bf(v.y), f2bf(v.z), f2bf(v.w) };
  *(u16x4*)(xb + (size_t)i*4) = o;
}

__global__ void k_conv_w(const float* __restrict__ Wf, const float* __restrict__ Wi,
                         const float* __restrict__ Wg, const float* __restrict__ Wo,
                         unsigned short* __restrict__ Wxb, unsigned short* __restrict__ Whb){
  int i = blockIdx.x*blockDim.x + threadIdx.x;
  if (i >= 3072*192) return;
  int gj = i / 192; int kc = (i % 192)*4;
  int g = gj / 768, j = gj % 768;
  const float* W = (g==0)?Wf:(g==1)?Wi:(g==2)?Wg:Wo;
  float4 vx = *(const float4*)(W + (size_t)j*1536 + kc);
  float4 vh = *(const float4*)(W + (size_t)j*1536 + 768 + kc);
  u16x4 ox = {f2bf(vx.x),f2bf(vx.y),f2bf(vx.z),f2bf(vx.w)};
  u16x4 oh = {f2bf(vh.x),f2bf(vh.y),f2bf(vh.z),f2bf(vh.w)};
  *(u16x4*)(Wxb + (size_t)gj*768 + kc) = ox;
  *(u16x4*)(Whb + (size_t)gj*768 + kc) = oh;
}

__global__ void k_conv_b(const float* __restrict__ b0, const float* __restrict__ b1,
                         const float* __restrict__ b2, const float* __restrict__ b3,
                         float* __restrict__ ball){
  int i = blockIdx.x*blockDim.x + threadIdx.x;
  if (i >= 3072) return;
  int g = i/768, j = i%768;
  const float* b = (g==0)?b0:(g==1)?b1:(g==2)?b2:b3;
  ball[i] = b[j];
}

// ---- phase 1: Xg[t][gj][b] = (x @ Wx^T), bf16, no bias ----
__global__ __launch_bounds__(256) void k_gemm_x(const unsigned short* __restrict__ xb,
        const unsigned short* __restrict__ Wxb, unsigned short* __restrict__ Xg){
  __shared__ __align__(16) short Ald[128*32];
  __shared__ __align__(16) short Bld[128*32];
  int blk = blockIdx.x;
  int bm = blk / 24, bn = blk % 24;     // consecutive blocks share A-panel (L2)
  size_t Mbase = (size_t)bm*128; int Nbase = bn*128;
  int tid = threadIdx.x; int w = tid>>6, l = tid&63;
  int wm = w&1, wn = w>>1, lr = l&15, lg = l>>4;
  f32x4 acc[4][4];
  #pragma unroll
  for (int a=0;a<4;++a)
    #pragma unroll
    for(int b2=0;b2<4;++b2) acc[a][b2] = (f32x4){0.f,0.f,0.f,0.f};
  int c0i = tid, c1i = tid+256;
  int r0 = c0i>>2, o0 = (c0i&3)*8;
  int r1 = c1i>>2, o1 = (c1i&3)*8;
  for (int kt=0; kt<24; ++kt) {
    int k0 = kt*32;
    short8 a0 = *(const short8*)(xb + (Mbase + r0)*768 + k0 + o0);
    short8 a1 = *(const short8*)(xb + (Mbase + r1)*768 + k0 + o1);
    short8 b0 = *(const short8*)(Wxb + (size_t)(Nbase + r0)*768 + k0 + o0);
    short8 b1 = *(const short8*)(Wxb + (size_t)(Nbase + r1)*768 + k0 + o1);
    __syncthreads();
    *(short8*)(Ald + r0*32 + o0) = a0;
    *(short8*)(Ald + r1*32 + o1) = a1;
    *(short8*)(Bld + r0*32 + o0) = b0;
    *(short8*)(Bld + r1*32 + o1) = b1;
    __syncthreads();
    short8 af[4], bfr[4];
    #pragma unroll
    for (int mi=0;mi<4;++mi) af[mi] = *(const short8*)(Ald + (wm*64+mi*16+lr)*32 + lg*8);
    #pragma unroll
    for (int ni=0;ni<4;++ni) bfr[ni] = *(const short8*)(Bld + (wn*64+ni*16+lr)*32 + lg*8);
    #pragma unroll
    for (int mi=0;mi<4;++mi)
      #pragma unroll
      for (int ni=0;ni<4;++ni)
        acc[mi][ni] = mfma16(af[mi], bfr[ni], acc[mi][ni]);
  }
  #pragma unroll
  for (int mi=0;mi<4;++mi){
    int m0 = (int)Mbase + wm*64 + mi*16 + lg*4;
    int t = m0>>6, b = m0&63;
    #pragma unroll
    for (int ni=0;ni<4;++ni){
      int col = Nbase + wn*64 + ni*16 + lr;
      u16x4 u = { f2bf(acc[mi][ni][0]), f2bf(acc[mi][ni][1]),
                  f2bf(acc[mi][ni][2]), f2bf(acc[mi][ni][3]) };
      *(u16x4*)(Xg + ((size_t)t*3072 + col)*64 + b) = u;
    }
  }
}

// ---- phase 2: persistent recurrent kernel. 96 WGs x 512 threads (8 waves:
// m in 0..3 x nh in 0..1). Wh fragments live in REGISTERS (staged once,
// reused 512x) -> no LDS, no intra-step syncthreads, and the per-step
// acquire-fence L2 invalidation costs nothing (no hot L2 state).
// One bounded-spin device barrier per step; h double-buffered in global bf16.
__global__ __launch_bounds__(512, 2) void k_lstm(const unsigned short* __restrict__ Xg,
     const unsigned short* __restrict__ Whb, const float* __restrict__ ball,
     unsigned short* __restrict__ hbuf, float* __restrict__ out, int* __restrict__ flags){
  int s = blockIdx.x, tid = threadIdx.x;
  int w8 = tid>>6, l = tid&63;
  int m = w8 & 3, nh = w8 >> 2;
  int n0 = l & 15, lg = l >> 4;
  int gate = n0 >> 2;
  int j = s*8 + nh*4 + (n0 & 3);
  size_t gj = (size_t)gate*768 + j;

  // stage this lane's 24 Wh B-fragments into registers (once, 512 reuses)
  short8 barr[24];
  #pragma unroll
  for (int kk=0; kk<24; ++kk)
    barr[kk] = *(const short8*)(Whb + gj*768 + kk*32 + lg*8);
  float bias = ball[gj];
  float cst[4] = {0.f, 0.f, 0.f, 0.f};
  int arow = m*16 + n0;
  int b4 = m*16 + lg*4;
  bool actv = (n0 < 4);

  for (int t=0; t<512; ++t){
    const unsigned short* hb = hbuf + (size_t)(t&1)*(64*768);
    unsigned short* hn = hbuf + (size_t)((t+1)&1)*(64*768);
    // A-fragments (h_t) from global: 24 independent 16B loads, then Xg
    short8 afr[24];
    #pragma unroll
    for (int kk=0; kk<24; ++kk)
      afr[kk] = *(const short8*)(hb + arow*768 + kk*32 + lg*8);
    u16x4 xg = *(const u16x4*)(Xg + ((size_t)t*3072 + gj)*64 + b4);
    // two accumulator chains to halve dependent-MFMA latency
    f32x4 acc0 = {0.f,0.f,0.f,0.f}, acc1 = {0.f,0.f,0.f,0.f};
    #pragma unroll
    for (int kk=0; kk<24; kk+=2){
      acc0 = mfma16(afr[kk],   barr[kk],   acc0);
      acc1 = mfma16(afr[kk+1], barr[kk+1], acc1);
    }
    f32x4 acc = acc0 + acc1;
    // pre-activation + this lane's gate nonlinearity (gate==2 -> tanh)
    float av[4];
    #pragma unroll
    for (int r=0; r<4; ++r){
      float pre = acc[r] + bf2f(xg[r]) + bias;
      av[r] = (gate == 2) ? tanh_s(pre) : sigm(pre);
    }
    // gather i (xor4), g (xor8), o (xor12); f is lane-local for n0<4
    #pragma unroll
    for (int r=0; r<4; ++r){
      float iv = __shfl_xor(av[r], 4);
      float gv = __shfl_xor(av[r], 8);
      float ov = __shfl_xor(av[r], 12);
      if (actv){
        float cn = av[r]*cst[r] + iv*gv;
        cst[r] = cn;
        float hv = ov * tanh_s(cn);
        int b = b4 + r;
        out[((size_t)t*64 + b)*768 + j] = hv;
        hn[(size_t)b*768 + j] = f2bf(hv);
        if (t == 511){
          out[(512UL*64 + b)*768 + j] = hv;        // hT
          out[(512UL*64 + 64 + b)*768 + j] = cst[r]; // cT
        }
      }
    }
    if (t < 511){
      __threadfence();          // make h stores visible device-wide
      __syncthreads();          // all 8 waves' stores done before flagging
      if (tid == 0)
        __hip_atomic_store(&flags[s*16], t+1, __ATOMIC_RELEASE, __HIP_MEMORY_SCOPE_AGENT);
      // every wave polls independently (no second syncthreads needed)
      int tgt = t+1;
      // bounded spin: normal exit in a few polls; bound -> wrong-answer not hang
      for (int it=0; it<(1<<14); ++it){
        int f1 = __hip_atomic_load(&flags[l*16], __ATOMIC_RELAXED, __HIP_MEMORY_SCOPE_AGENT);
        int f2 = (l<32) ? __hip_atomic_load(&flags[(64+l)*16], __ATOMIC_RELAXED, __HIP_MEMORY_SCOPE_AGENT) : tgt;
        if (__all(f1>=tgt && f2>=tgt)) break;
        __builtin_amdgcn_s_sleep(2);
      }
      __builtin_amdgcn_fence(__ATOMIC_ACQUIRE, "agent"); // invalidate stale h
    }
  }
}

extern "C" void kernel_launch(void* const* d_in, const int* in_sizes, int n_in,
                              void* d_out, int out_size, void* d_ws, size_t ws_size,
                              hipStream_t stream){
  const float* x   = (const float*)d_in[0];
  const float* Wf  = (const float*)d_in[1];
  const float* bf_ = (const float*)d_in[2];
  const float* Wi  = (const float*)d_in[3];
  const float* bi_ = (const float*)d_in[4];
  const float* Wg  = (const float*)d_in[5];
  const float* bg_ = (const float*)d_in[6];
  const float* Wo  = (const float*)d_in[7];
  const float* bo_ = (const float*)d_in[8];
  char* ws = (char*)d_ws;
  if (ws_size < OFF_FLAGS + SZ_FLAGS) return;  // need ~262 MB scratch
  unsigned short* xb   = (unsigned short*)(ws + OFF_XBF);
  unsigned short* Wxb  = (unsigned short*)(ws + OFF_WXB);
  unsigned short* Whb  = (unsigned short*)(ws + OFF_WHB);
  float*          ball = (float*)(ws + OFF_BALL);
  unsigned short* Xg   = (unsigned short*)(ws + OFF_XG);
  unsigned short* hbuf = (unsigned short*)(ws + OFF_HBUF);
  int*            flags= (int*)(ws + OFF_FLAGS);
  float* out = (float*)d_out;

  // h0=0 and flags=0 every call (flags MUST reset between graph replays)
  (void)hipMemsetAsync(hbuf, 0, SZ_HBUF + SZ_FLAGS, stream);
  k_conv_x<<<24576, 256, 0, stream>>>(x, xb, 6291456);
  k_conv_w<<<2304, 256, 0, stream>>>(Wf, Wi, Wg, Wo, Wxb, Whb);
  k_conv_b<<<12, 256, 0, stream>>>(bf_, bi_, bg_, bo_, ball);
  k_gemm_x<<<6144, 256, 0, stream>>>(xb, Wxb, Xg);
  k_lstm<<<NWG, 512, 0, stream>>>(Xg, Whb, ball, hbuf, out, flags);
}

// Round 6
// 5789.331 us; speedup vs baseline: 2.9309x; 2.9309x over previous
//
#include <hip/hip_runtime.h>
#include <stdint.h>

typedef __attribute__((ext_vector_type(8))) short short8;
typedef __attribute__((ext_vector_type(4))) float f32x4;
typedef __attribute__((ext_vector_type(4))) unsigned short u16x4;

// Problem constants: T=512, B=64, D=768, H=768, 4H=3072
#define NWG 96

// ws layout (bytes, all 256-aligned)
#define OFF_XBF   0UL
#define SZ_XBF    (512UL*64*768*2)
#define OFF_WXB   (OFF_XBF + SZ_XBF)
#define SZ_WB     (3072UL*768*2)
#define OFF_WHB   (OFF_WXB + SZ_WB)
#define OFF_BALL  (OFF_WHB + SZ_WB)
#define SZ_BALL   (3072UL*4)
#define OFF_XG    (OFF_BALL + SZ_BALL)
#define SZ_XG     (512UL*3072*64*2)
#define OFF_HBUF  (OFF_XG + SZ_XG)
#define SZ_HBUF   (2UL*64*768*2)
#define OFF_FLAGS (OFF_HBUF + SZ_HBUF)
#define SZ_FLAGS  (NWG*4UL)

__device__ __forceinline__ float bf2f(unsigned short u){
  union{unsigned int i; float f;} v; v.i = ((unsigned int)u)<<16; return v.f;
}
__device__ __forceinline__ unsigned short f2bf(float f){
  union{float f; unsigned int i;} v; v.f = f;
  unsigned int x = v.i;
  return (unsigned short)((x + 0x7fffu + ((x>>16)&1u)) >> 16);
}
__device__ __forceinline__ float sigm(float x){ return 1.0f/(1.0f + __expf(-x)); }
// overflow-safe tanh: large |x| -> exp -> inf -> r=1, copysign fixes sign
__device__ __forceinline__ float tanh_s(float x){
  float e = __expf(2.0f*fabsf(x));
  float r = 1.0f - 2.0f/(e+1.0f);
  return copysignf(r, x);
}
__device__ __forceinline__ f32x4 mfma16(short8 a, short8 b, f32x4 c){
  return __builtin_amdgcn_mfma_f32_16x16x32_bf16(a, b, c, 0, 0, 0);
}
// L1+L2-bypassing accesses: data moves at the memory-side (IF$) coherence
// point, so cross-XCD visibility needs NO buffer_wbl2 / buffer_inv fences
// and the per-CU/XCD caches stay hot for Xg/Whb.
__device__ __forceinline__ short8 ld_b128_sc(const unsigned short* p){
  short8 r;
  asm volatile("global_load_dwordx4 %0, %1, off sc0 sc1"
               : "=&v"(r) : "v"(p) : "memory");
  return r;
}
__device__ __forceinline__ void st_b16_sc(unsigned short* p, unsigned int v){
  asm volatile("global_store_short %0, %1, off sc0 sc1"
               :: "v"(p), "v"(v) : "memory");
}

// ---- converters ----
__global__ void k_conv_x(const float* __restrict__ x, unsigned short* __restrict__ xb, int n4){
  int i = blockIdx.x*blockDim.x + threadIdx.x;
  if (i >= n4) return;
  float4 v = ((const float4*)x)[i];
  u16x4 o = { f2bf(v.x), f2bf(v.y), f2bf(v.z), f2bf(v.w) };
  *(u16x4*)(xb + (size_t)i*4) = o;
}

__global__ void k_conv_w(const float* __restrict__ Wf, const float* __restrict__ Wi,
                         const float* __restrict__ Wg, const float* __restrict__ Wo,
                         unsigned short* __restrict__ Wxb, unsigned short* __restrict__ Whb){
  int i = blockIdx.x*blockDim.x + threadIdx.x;
  if (i >= 3072*192) return;
  int gj = i / 192; int kc = (i % 192)*4;
  int g = gj / 768, j = gj % 768;
  const float* W = (g==0)?Wf:(g==1)?Wi:(g==2)?Wg:Wo;
  float4 vx = *(const float4*)(W + (size_t)j*1536 + kc);
  float4 vh = *(const float4*)(W + (size_t)j*1536 + 768 + kc);
  u16x4 ox = {f2bf(vx.x),f2bf(vx.y),f2bf(vx.z),f2bf(vx.w)};
  u16x4 oh = {f2bf(vh.x),f2bf(vh.y),f2bf(vh.z),f2bf(vh.w)};
  *(u16x4*)(Wxb + (size_t)gj*768 + kc) = ox;
  *(u16x4*)(Whb + (size_t)gj*768 + kc) = oh;
}

__global__ void k_conv_b(const float* __restrict__ b0, const float* __restrict__ b1,
                         const float* __restrict__ b2, const float* __restrict__ b3,
                         float* __restrict__ ball){
  int i = blockIdx.x*blockDim.x + threadIdx.x;
  if (i >= 3072) return;
  int g = i/768, j = i%768;
  const float* b = (g==0)?b0:(g==1)?b1:(g==2)?b2:b3;
  ball[i] = b[j];
}

// ---- phase 1: Xg[t][gj][b] = (x @ Wx^T), bf16, no bias ----
__global__ __launch_bounds__(256) void k_gemm_x(const unsigned short* __restrict__ xb,
        const unsigned short* __restrict__ Wxb, unsigned short* __restrict__ Xg){
  __shared__ __align__(16) short Ald[128*32];
  __shared__ __align__(16) short Bld[128*32];
  int blk = blockIdx.x;
  int bm = blk / 24, bn = blk % 24;     // consecutive blocks share A-panel (L2)
  size_t Mbase = (size_t)bm*128; int Nbase = bn*128;
  int tid = threadIdx.x; int w = tid>>6, l = tid&63;
  int wm = w&1, wn = w>>1, lr = l&15, lg = l>>4;
  f32x4 acc[4][4];
  #pragma unroll
  for (int a=0;a<4;++a)
    #pragma unroll
    for(int b2=0;b2<4;++b2) acc[a][b2] = (f32x4){0.f,0.f,0.f,0.f};
  int c0i = tid, c1i = tid+256;
  int r0 = c0i>>2, o0 = (c0i&3)*8;
  int r1 = c1i>>2, o1 = (c1i&3)*8;
  for (int kt=0; kt<24; ++kt) {
    int k0 = kt*32;
    short8 a0 = *(const short8*)(xb + (Mbase + r0)*768 + k0 + o0);
    short8 a1 = *(const short8*)(xb + (Mbase + r1)*768 + k0 + o1);
    short8 b0 = *(const short8*)(Wxb + (size_t)(Nbase + r0)*768 + k0 + o0);
    short8 b1 = *(const short8*)(Wxb + (size_t)(Nbase + r1)*768 + k0 + o1);
    __syncthreads();
    *(short8*)(Ald + r0*32 + o0) = a0;
    *(short8*)(Ald + r1*32 + o1) = a1;
    *(short8*)(Bld + r0*32 + o0) = b0;
    *(short8*)(Bld + r1*32 + o1) = b1;
    __syncthreads();
    short8 af[4], bfr[4];
    #pragma unroll
    for (int mi=0;mi<4;++mi) af[mi] = *(const short8*)(Ald + (wm*64+mi*16+lr)*32 + lg*8);
    #pragma unroll
    for (int ni=0;ni<4;++ni) bfr[ni] = *(const short8*)(Bld + (wn*64+ni*16+lr)*32 + lg*8);
    #pragma unroll
    for (int mi=0;mi<4;++mi)
      #pragma unroll
      for (int ni=0;ni<4;++ni)
        acc[mi][ni] = mfma16(af[mi], bfr[ni], acc[mi][ni]);
  }
  #pragma unroll
  for (int mi=0;mi<4;++mi){
    int m0 = (int)Mbase + wm*64 + mi*16 + lg*4;
    int t = m0>>6, b = m0&63;
    #pragma unroll
    for (int ni=0;ni<4;++ni){
      int col = Nbase + wn*64 + ni*16 + lr;
      u16x4 u = { f2bf(acc[mi][ni][0]), f2bf(acc[mi][ni][1]),
                  f2bf(acc[mi][ni][2]), f2bf(acc[mi][ni][3]) };
      *(u16x4*)(Xg + ((size_t)t*3072 + col)*64 + b) = u;
    }
  }
}

// ---- phase 2: persistent recurrent kernel. 96 WGs x 512 threads (8 waves).
// Wh register-resident (launch_bounds(512,1) -> 256 VGPR budget).
// NO cache-wide fences: h + flags move through IF$ via sc0|sc1 bypass
// accesses; __syncthreads' per-wave vmcnt(0) drain orders h-store-acks
// before the relaxed flag store. One bounded-spin barrier per step.
__global__ __launch_bounds__(512, 1) void k_lstm(const unsigned short* __restrict__ Xg,
     const unsigned short* __restrict__ Whb, const float* __restrict__ ball,
     unsigned short* __restrict__ hbuf, float* __restrict__ out, int* __restrict__ flags){
  int s = blockIdx.x, tid = threadIdx.x;
  int w8 = tid>>6, l = tid&63;
  int m = w8 & 3, nh = w8 >> 2;
  int n0 = l & 15, lg = l >> 4;
  int gate = n0 >> 2;
  int j = s*8 + nh*4 + (n0 & 3);
  size_t gj = (size_t)gate*768 + j;

  // stage this lane's 24 Wh B-fragments into registers (once, 512 reuses)
  short8 barr[24];
  #pragma unroll
  for (int kk=0; kk<24; ++kk)
    barr[kk] = *(const short8*)(Whb + gj*768 + kk*32 + lg*8);
  float bias = ball[gj];
  float cst[4] = {0.f, 0.f, 0.f, 0.f};
  int arow = m*16 + n0;
  int b4 = m*16 + lg*4;
  bool actv = (n0 < 4);
  u16x4 xg = *(const u16x4*)(Xg + gj*64 + b4);   // t=0 prefetch

  for (int t=0; t<512; ++t){
    const unsigned short* hb = hbuf + (size_t)(t&1)*(64*768);
    unsigned short* hn = hbuf + (size_t)((t+1)&1)*(64*768);
    // A-fragments (h_t): 24 independent L1/L2-bypass 16B loads from IF$
    short8 afr[24];
    #pragma unroll
    for (int kk=0; kk<24; ++kk)
      afr[kk] = ld_b128_sc(hb + arow*768 + kk*32 + lg*8);
    asm volatile("s_waitcnt vmcnt(0)" ::: "memory");
    __builtin_amdgcn_sched_barrier(0);   // rule #18: pin MFMA after the wait
    // two accumulator chains to halve dependent-MFMA latency
    f32x4 acc0 = {0.f,0.f,0.f,0.f}, acc1 = {0.f,0.f,0.f,0.f};
    #pragma unroll
    for (int kk=0; kk<24; kk+=2){
      acc0 = mfma16(afr[kk],   barr[kk],   acc0);
      acc1 = mfma16(afr[kk+1], barr[kk+1], acc1);
    }
    f32x4 acc = acc0 + acc1;
    // pre-activation + this lane's gate nonlinearity (gate==2 -> tanh)
    float av[4];
    #pragma unroll
    for (int r=0; r<4; ++r){
      float pre = acc[r] + bf2f(xg[r]) + bias;
      av[r] = (gate == 2) ? tanh_s(pre) : sigm(pre);
    }
    // gather i (xor4), g (xor8), o (xor12); f is lane-local for n0<4
    #pragma unroll
    for (int r=0; r<4; ++r){
      float iv = __shfl_xor(av[r], 4);
      float gv = __shfl_xor(av[r], 8);
      float ov = __shfl_xor(av[r], 12);
      if (actv){
        float cn = av[r]*cst[r] + iv*gv;
        cst[r] = cn;
        float hv = ov * tanh_s(cn);
        int b = b4 + r;
        out[((size_t)t*64 + b)*768 + j] = hv;          // normal cached store
        st_b16_sc(hn + (size_t)b*768 + j, (unsigned int)f2bf(hv)); // IF$ store
        if (t == 511){
          out[(512UL*64 + b)*768 + j] = hv;            // hT
          out[(512UL*64 + 64 + b)*768 + j] = cst[r];   // cT
        }
      }
    }
    if (t < 511){
      // per-wave drain: all sc1 h-stores acked at IF$ before the barrier
      asm volatile("s_waitcnt vmcnt(0)" ::: "memory");
      __syncthreads();
      if (tid == 0)
        __hip_atomic_store(&flags[s], t+1, __ATOMIC_RELAXED, __HIP_MEMORY_SCOPE_AGENT);
      // prefetch next step's Xg (cached; overlaps the poll wait)
      u16x4 xgn = *(const u16x4*)(Xg + ((size_t)(t+1)*3072 + gj)*64 + b4);
      int tgt = t+1;
      // bounded spin: normal exit in a few polls; bound -> wrong-answer not hang
      for (int it=0; it<(1<<14); ++it){
        int f1 = __hip_atomic_load(&flags[l], __ATOMIC_RELAXED, __HIP_MEMORY_SCOPE_AGENT);
        int f2 = (l<32) ? __hip_atomic_load(&flags[64+l], __ATOMIC_RELAXED, __HIP_MEMORY_SCOPE_AGENT) : tgt;
        if (__all(f1>=tgt && f2>=tgt)) break;
        __builtin_amdgcn_s_sleep(1);
      }
      xg = xgn;
    }
  }
}

extern "C" void kernel_launch(void* const* d_in, const int* in_sizes, int n_in,
                              void* d_out, int out_size, void* d_ws, size_t ws_size,
                              hipStream_t stream){
  const float* x   = (const float*)d_in[0];
  const float* Wf  = (const float*)d_in[1];
  const float* bf_ = (const float*)d_in[2];
  const float* Wi  = (const float*)d_in[3];
  const float* bi_ = (const float*)d_in[4];
  const float* Wg  = (const float*)d_in[5];
  const float* bg_ = (const float*)d_in[6];
  const float* Wo  = (const float*)d_in[7];
  const float* bo_ = (const float*)d_in[8];
  char* ws = (char*)d_ws;
  if (ws_size < OFF_FLAGS + SZ_FLAGS) return;  // need ~262 MB scratch
  unsigned short* xb   = (unsigned short*)(ws + OFF_XBF);
  unsigned short* Wxb  = (unsigned short*)(ws + OFF_WXB);
  unsigned short* Whb  = (unsigned short*)(ws + OFF_WHB);
  float*          ball = (float*)(ws + OFF_BALL);
  unsigned short* Xg   = (unsigned short*)(ws + OFF_XG);
  unsigned short* hbuf = (unsigned short*)(ws + OFF_HBUF);
  int*            flags= (int*)(ws + OFF_FLAGS);
  float* out = (float*)d_out;

  // h0=0 and flags=0 every call (flags MUST reset between graph replays)
  (void)hipMemsetAsync(hbuf, 0, SZ_HBUF + SZ_FLAGS, stream);
  k_conv_x<<<24576, 256, 0, stream>>>(x, xb, 6291456);
  k_conv_w<<<2304, 256, 0, stream>>>(Wf, Wi, Wg, Wo, Wxb, Whb);
  k_conv_b<<<12, 256, 0, stream>>>(bf_, bi_, bg_, bo_, ball);
  k_gemm_x<<<6144, 256, 0, stream>>>(xb, Wxb, Xg);
  k_lstm<<<NWG, 512, 0, stream>>>(Xg, Whb, ball, hbuf, out, flags);
}

// Round 7
// 4822.880 us; speedup vs baseline: 3.5182x; 1.2004x over previous
//
#include <hip/hip_runtime.h>
#include <stdint.h>

typedef __attribute__((ext_vector_type(8))) short short8;
typedef __attribute__((ext_vector_type(4))) float f32x4;
typedef __attribute__((ext_vector_type(4))) unsigned short u16x4;

// Problem constants: T=512, B=64, D=768, H=768, 4H=3072
#define NWG 96

// ws layout (bytes, all 256-aligned)
#define OFF_XBF   0UL
#define SZ_XBF    (512UL*64*768*2)
#define OFF_WXB   (OFF_XBF + SZ_XBF)
#define SZ_WB     (3072UL*768*2)
#define OFF_WHB   (OFF_WXB + SZ_WB)
#define OFF_BALL  (OFF_WHB + SZ_WB)
#define SZ_BALL   (3072UL*4)
#define OFF_XG    (OFF_BALL + SZ_BALL)
#define SZ_XG     (512UL*3072*64*2)
#define OFF_HBUF  (OFF_XG + SZ_XG)
#define SZ_HBUF   (2UL*64*768*2)
#define OFF_FLAGS (OFF_HBUF + SZ_HBUF)
#define SZ_FLAGS  (NWG*16UL*4)

__device__ __forceinline__ float bf2f(unsigned short u){
  union{unsigned int i; float f;} v; v.i = ((unsigned int)u)<<16; return v.f;
}
__device__ __forceinline__ unsigned short f2bf(float f){
  union{float f; unsigned int i;} v; v.f = f;
  unsigned int x = v.i;
  return (unsigned short)((x + 0x7fffu + ((x>>16)&1u)) >> 16);
}
__device__ __forceinline__ float sigm(float x){ return 1.0f/(1.0f + __expf(-x)); }
// overflow-safe tanh: large |x| -> exp -> inf -> r=1, copysign fixes sign
__device__ __forceinline__ float tanh_s(float x){
  float e = __expf(2.0f*fabsf(x));
  float r = 1.0f - 2.0f/(e+1.0f);
  return copysignf(r, x);
}
__device__ __forceinline__ f32x4 mfma16(short8 a, short8 b, f32x4 c){
  return __builtin_amdgcn_mfma_f32_16x16x32_bf16(a, b, c, 0, 0, 0);
}
// L1+L2-bypassing accesses: data moves at the memory-side (IF$) coherence
// point -> cross-XCD visibility without any buffer_wbl2/buffer_inv fences,
// and the per-XCD caches stay hot for Xg.
__device__ __forceinline__ short8 ld_b128_sc(const unsigned short* p){
  short8 r;
  asm volatile("global_load_dwordx4 %0, %1, off sc0 sc1"
               : "=&v"(r) : "v"(p) : "memory");
  return r;
}
__device__ __forceinline__ void st_b128_sc(unsigned short* p, short8 v){
  asm volatile("global_store_dwordx4 %0, %1, off sc0 sc1"
               :: "v"(p), "v"(v) : "memory");
}

// ---- converters ----
__global__ void k_conv_x(const float* __restrict__ x, unsigned short* __restrict__ xb, int n4){
  int i = blockIdx.x*blockDim.x + threadIdx.x;
  if (i >= n4) return;
  float4 v = ((const float4*)x)[i];
  u16x4 o = { f2bf(v.x), f2bf(v.y), f2bf(v.z), f2bf(v.w) };
  *(u16x4*)(xb + (size_t)i*4) = o;
}

__global__ void k_conv_w(const float* __restrict__ Wf, const float* __restrict__ Wi,
                         const float* __restrict__ Wg, const float* __restrict__ Wo,
                         unsigned short* __restrict__ Wxb, unsigned short* __restrict__ Whb){
  int i = blockIdx.x*blockDim.x + threadIdx.x;
  if (i >= 3072*192) return;
  int gj = i / 192; int kc = (i % 192)*4;
  int g = gj / 768, j = gj % 768;
  const float* W = (g==0)?Wf:(g==1)?Wi:(g==2)?Wg:Wo;
  float4 vx = *(const float4*)(W + (size_t)j*1536 + kc);
  float4 vh = *(const float4*)(W + (size_t)j*1536 + 768 + kc);
  u16x4 ox = {f2bf(vx.x),f2bf(vx.y),f2bf(vx.z),f2bf(vx.w)};
  u16x4 oh = {f2bf(vh.x),f2bf(vh.y),f2bf(vh.z),f2bf(vh.w)};
  *(u16x4*)(Wxb + (size_t)gj*768 + kc) = ox;
  *(u16x4*)(Whb + (size_t)gj*768 + kc) = oh;
}

__global__ void k_conv_b(const float* __restrict__ b0, const float* __restrict__ b1,
                         const float* __restrict__ b2, const float* __restrict__ b3,
                         float* __restrict__ ball){
  int i = blockIdx.x*blockDim.x + threadIdx.x;
  if (i >= 3072) return;
  int g = i/768, j = i%768;
  const float* b = (g==0)?b0:(g==1)?b1:(g==2)?b2:b3;
  ball[i] = b[j];
}

// ---- phase 1: Xg[t][gj][b] = (x @ Wx^T), bf16, no bias ----
__global__ __launch_bounds__(256) void k_gemm_x(const unsigned short* __restrict__ xb,
        const unsigned short* __restrict__ Wxb, unsigned short* __restrict__ Xg){
  __shared__ __align__(16) short Ald[128*32];
  __shared__ __align__(16) short Bld[128*32];
  int blk = blockIdx.x;
  int bm = blk / 24, bn = blk % 24;     // consecutive blocks share A-panel (L2)
  size_t Mbase = (size_t)bm*128; int Nbase = bn*128;
  int tid = threadIdx.x; int w = tid>>6, l = tid&63;
  int wm = w&1, wn = w>>1, lr = l&15, lg = l>>4;
  f32x4 acc[4][4];
  #pragma unroll
  for (int a=0;a<4;++a)
    #pragma unroll
    for(int b2=0;b2<4;++b2) acc[a][b2] = (f32x4){0.f,0.f,0.f,0.f};
  int c0i = tid, c1i = tid+256;
  int r0 = c0i>>2, o0 = (c0i&3)*8;
  int r1 = c1i>>2, o1 = (c1i&3)*8;
  for (int kt=0; kt<24; ++kt) {
    int k0 = kt*32;
    short8 a0 = *(const short8*)(xb + (Mbase + r0)*768 + k0 + o0);
    short8 a1 = *(const short8*)(xb + (Mbase + r1)*768 + k0 + o1);
    short8 b0 = *(const short8*)(Wxb + (size_t)(Nbase + r0)*768 + k0 + o0);
    short8 b1 = *(const short8*)(Wxb + (size_t)(Nbase + r1)*768 + k0 + o1);
    __syncthreads();
    *(short8*)(Ald + r0*32 + o0) = a0;
    *(short8*)(Ald + r1*32 + o1) = a1;
    *(short8*)(Bld + r0*32 + o0) = b0;
    *(short8*)(Bld + r1*32 + o1) = b1;
    __syncthreads();
    short8 af[4], bfr[4];
    #pragma unroll
    for (int mi=0;mi<4;++mi) af[mi] = *(const short8*)(Ald + (wm*64+mi*16+lr)*32 + lg*8);
    #pragma unroll
    for (int ni=0;ni<4;++ni) bfr[ni] = *(const short8*)(Bld + (wn*64+ni*16+lr)*32 + lg*8);
    #pragma unroll
    for (int mi=0;mi<4;++mi)
      #pragma unroll
      for (int ni=0;ni<4;++ni)
        acc[mi][ni] = mfma16(af[mi], bfr[ni], acc[mi][ni]);
  }
  #pragma unroll
  for (int mi=0;mi<4;++mi){
    int m0 = (int)Mbase + wm*64 + mi*16 + lg*4;
    int t = m0>>6, b = m0&63;
    #pragma unroll
    for (int ni=0;ni<4;++ni){
      int col = Nbase + wn*64 + ni*16 + lr;
      u16x4 u = { f2bf(acc[mi][ni][0]), f2bf(acc[mi][ni][1]),
                  f2bf(acc[mi][ni][2]), f2bf(acc[mi][ni][3]) };
      *(u16x4*)(Xg + ((size_t)t*3072 + col)*64 + b) = u;
    }
  }
}

// ---- phase 2: persistent recurrent kernel. 96 WGs x 512 threads (8 waves).
// Wh in LDS (immune to asm "memory"-clobber reloads). h stores packed via a
// 1KB LDS tile and emitted by wave 7 ONLY (64 coalesced 16B sc-stores), so
// the pre-flag vmcnt drain covers just those. Wave 0 alone polls the 96
// 64B-strided flags; a syncthreads releases the WG. No cache-wide fences.
__global__ __launch_bounds__(512, 1) void k_lstm(const unsigned short* __restrict__ Xg,
     const unsigned short* __restrict__ Whb, const float* __restrict__ ball,
     unsigned short* __restrict__ hbuf, float* __restrict__ out, int* __restrict__ flags){
  __shared__ __align__(16) short Wl[32*776];          // Wh slice (2-way aliasing only)
  __shared__ __align__(16) unsigned short hl[64*8];   // h pack tile
  int s = blockIdx.x, tid = threadIdx.x;
  int w8 = tid>>6, l = tid&63;
  int m = w8 & 3, nh = w8 >> 2;
  int n0 = l & 15, lg = l >> 4;
  int gate = n0 >> 2;
  int jj4 = nh*4 + (n0 & 3);           // 0..7 within this WG's j-slice
  int j = s*8 + jj4;
  size_t gj = (size_t)gate*768 + j;
  int rB = jj4*4 + gate;               // LDS row: gates interleaved -> 2-way banks

  // stage Wh slice once: Wl[rB][k] = Whb[gate*768 + s*8 + jj][k]
  for (int c = tid; c < 3072; c += 512){
    int r = c/96, off = (c%96)*8;
    int gt = r & 3, jq = r >> 2;
    short8 v = *(const short8*)(Whb + ((size_t)(gt*768 + s*8 + jq))*768 + off);
    *(short8*)(Wl + r*776 + off) = v;
  }
  __syncthreads();

  float bias = ball[gj];
  float cst[4] = {0.f, 0.f, 0.f, 0.f};
  int arow = m*16 + n0;
  int b4 = m*16 + lg*4;
  bool actv = (n0 < 4);
  u16x4 xg = *(const u16x4*)(Xg + gj*64 + b4);   // t=0 prefetch

  for (int t=0; t<512; ++t){
    const unsigned short* hb = hbuf + (size_t)(t&1)*(64*768);
    unsigned short* hn = hbuf + (size_t)((t+1)&1)*(64*768);
    // A-fragments (h_t): 24 L1/L2-bypass 16B loads (read at IF$)
    short8 afr[24];
    #pragma unroll
    for (int kk=0; kk<24; ++kk)
      afr[kk] = ld_b128_sc(hb + arow*768 + kk*32 + lg*8);
    asm volatile("s_waitcnt vmcnt(0)" ::: "memory");
    __builtin_amdgcn_sched_barrier(0);   // rule #18: keep MFMA after the wait
    // MFMA with B streamed from LDS; two acc chains for latency
    f32x4 acc0 = {0.f,0.f,0.f,0.f}, acc1 = {0.f,0.f,0.f,0.f};
    #pragma unroll
    for (int kk=0; kk<24; kk+=2){
      short8 b0 = *(const short8*)(Wl + rB*776 + kk*32 + lg*8);
      short8 b1 = *(const short8*)(Wl + rB*776 + (kk+1)*32 + lg*8);
      acc0 = mfma16(afr[kk],   b0, acc0);
      acc1 = mfma16(afr[kk+1], b1, acc1);
    }
    f32x4 acc = acc0 + acc1;
    // pre-activation + this lane's gate nonlinearity (gate==2 -> tanh)
    float av[4];
    #pragma unroll
    for (int r=0; r<4; ++r){
      float pre = acc[r] + bf2f(xg[r]) + bias;
      av[r] = (gate == 2) ? tanh_s(pre) : sigm(pre);
    }
    // gather i (xor4), g (xor8), o (xor12); f is lane-local for n0<4
    float hvv[4];
    #pragma unroll
    for (int r=0; r<4; ++r){
      float iv = __shfl_xor(av[r], 4);
      float gv = __shfl_xor(av[r], 8);
      float ov = __shfl_xor(av[r], 12);
      float cn = av[r]*cst[r] + iv*gv;
      float hv = ov * tanh_s(cn);
      if (actv){
        cst[r] = cn;
        hvv[r] = hv;
        if (t < 511) hl[(b4 + r)*8 + jj4] = f2bf(hv);  // pack tile (j = s*8+jj4)
      }
    }
    if (t < 511){
      __syncthreads();                   // hl complete
      if (w8 == 7){
        // 64 coalesced 16B h-stores; ONLY these gate the flag (per-wave vmcnt)
        short8 hp = *(const short8*)(hl + l*8);
        st_b128_sc(hn + (size_t)l*768 + s*8, hp);
        asm volatile("s_waitcnt vmcnt(0)" ::: "memory");
        if (l == 0)
          __hip_atomic_store(&flags[s*16], t+1, __ATOMIC_RELAXED, __HIP_MEMORY_SCOPE_AGENT);
      }
      // out stores don't gate the flag (other waves; wave7 issues post-flag)
      if (actv){
        #pragma unroll
        for (int r=0; r<4; ++r)
          out[((size_t)t*64 + b4 + r)*768 + j] = hvv[r];
      }
      u16x4 xgn = *(const u16x4*)(Xg + ((size_t)(t+1)*3072 + gj)*64 + b4);
      if (w8 == 0){
        int tgt = t+1;
        // bounded spin: wave 0 only; bound -> wrong-answer not hang
        for (int it=0; it<(1<<14); ++it){
          int f1 = __hip_atomic_load(&flags[l*16], __ATOMIC_RELAXED, __HIP_MEMORY_SCOPE_AGENT);
          int f2 = (l<32) ? __hip_atomic_load(&flags[(64+l)*16], __ATOMIC_RELAXED, __HIP_MEMORY_SCOPE_AGENT) : tgt;
          if (__all(f1>=tgt && f2>=tgt)) break;
          __builtin_amdgcn_s_sleep(1);
        }
      }
      __syncthreads();                   // release: all 96 flags >= t+1
      xg = xgn;
    } else if (actv){
      #pragma unroll
      for (int r=0; r<4; ++r){
        int b = b4 + r;
        out[((size_t)t*64 + b)*768 + j] = hvv[r];
        out[(512UL*64 + b)*768 + j] = hvv[r];        // hT
        out[(512UL*64 + 64 + b)*768 + j] = cst[r];   // cT
      }
    }
  }
}

extern "C" void kernel_launch(void* const* d_in, const int* in_sizes, int n_in,
                              void* d_out, int out_size, void* d_ws, size_t ws_size,
                              hipStream_t stream){
  const float* x   = (const float*)d_in[0];
  const float* Wf  = (const float*)d_in[1];
  const float* bf_ = (const float*)d_in[2];
  const float* Wi  = (const float*)d_in[3];
  const float* bi_ = (const float*)d_in[4];
  const float* Wg  = (const float*)d_in[5];
  const float* bg_ = (const float*)d_in[6];
  const float* Wo  = (const float*)d_in[7];
  const float* bo_ = (const float*)d_in[8];
  char* ws = (char*)d_ws;
  if (ws_size < OFF_FLAGS + SZ_FLAGS) return;  // need ~262 MB scratch
  unsigned short* xb   = (unsigned short*)(ws + OFF_XBF);
  unsigned short* Wxb  = (unsigned short*)(ws + OFF_WXB);
  unsigned short* Whb  = (unsigned short*)(ws + OFF_WHB);
  float*          ball = (float*)(ws + OFF_BALL);
  unsigned short* Xg   = (unsigned short*)(ws + OFF_XG);
  unsigned short* hbuf = (unsigned short*)(ws + OFF_HBUF);
  int*            flags= (int*)(ws + OFF_FLAGS);
  float* out = (float*)d_out;

  // h0=0 and flags=0 every call (flags MUST reset between graph replays)
  (void)hipMemsetAsync(hbuf, 0, SZ_HBUF + SZ_FLAGS, stream);
  k_conv_x<<<24576, 256, 0, stream>>>(x, xb, 6291456);
  k_conv_w<<<2304, 256, 0, stream>>>(Wf, Wi, Wg, Wo, Wxb, Whb);
  k_conv_b<<<12, 256, 0, stream>>>(bf_, bi_, bg_, bo_, ball);
  k_gemm_x<<<6144, 256, 0, stream>>>(xb, Wxb, Xg);
  k_lstm<<<NWG, 512, 0, stream>>>(Xg, Whb, ball, hbuf, out, flags);
}

// Round 8
// 4543.930 us; speedup vs baseline: 3.7342x; 1.0614x over previous
//
#include <hip/hip_runtime.h>
#include <stdint.h>

typedef __attribute__((ext_vector_type(8))) short short8;
typedef __attribute__((ext_vector_type(4))) float f32x4;
typedef __attribute__((ext_vector_type(4))) unsigned short u16x4;

// Problem constants: T=512, B=64, D=768, H=768, 4H=3072
#define NWG 96

// ws layout (bytes, all 256-aligned)
#define OFF_XBF   0UL
#define SZ_XBF    (512UL*64*768*2)      // xb; REUSED as 512 per-t h buffers by k_lstm
#define OFF_WXB   (OFF_XBF + SZ_XBF)
#define SZ_WB     (3072UL*768*2)        // Wxb; REUSED as per-t flags by k_lstm
#define OFF_WHB   (OFF_WXB + SZ_WB)
#define OFF_BALL  (OFF_WHB + SZ_WB)
#define SZ_BALL   (3072UL*4)
#define OFF_XG    (OFF_BALL + SZ_BALL)
#define SZ_XG     (512UL*3072*64*2)
#define OFF_END   (OFF_XG + SZ_XG)

// per-t h buffer: 64x768 bf16 = 98304 B; 512 of them = SZ_XBF exactly.
#define HSTRIDE   49152               // shorts per h buffer
// per-t flags: 96 x 64B = 6144 B (1536 ints); 512 steps = 3.1 MB < SZ_WB.
#define FSTRIDE   1536                // ints per step

__device__ __forceinline__ float bf2f(unsigned short u){
  union{unsigned int i; float f;} v; v.i = ((unsigned int)u)<<16; return v.f;
}
__device__ __forceinline__ unsigned short f2bf(float f){
  union{float f; unsigned int i;} v; v.f = f;
  unsigned int x = v.i;
  return (unsigned short)((x + 0x7fffu + ((x>>16)&1u)) >> 16);
}
__device__ __forceinline__ float sigm(float x){ return 1.0f/(1.0f + __expf(-x)); }
// overflow-safe tanh: large |x| -> exp -> inf -> r=1, copysign fixes sign
__device__ __forceinline__ float tanh_s(float x){
  float e = __expf(2.0f*fabsf(x));
  float r = 1.0f - 2.0f/(e+1.0f);
  return copysignf(r, x);
}
__device__ __forceinline__ f32x4 mfma16(short8 a, short8 b, f32x4 c){
  return __builtin_amdgcn_mfma_f32_16x16x32_bf16(a, b, c, 0, 0, 0);
}
// h producer stores bypass L1+L2 (reach the memory-side coherence point, no
// dirty local-L2 copies). Readers then use PLAIN cached loads on per-t
// addresses: never-reused addresses can't be stale in any cache.
__device__ __forceinline__ void st_b128_sc(unsigned short* p, short8 v){
  asm volatile("global_store_dwordx4 %0, %1, off sc0 sc1"
               :: "v"(p), "v"(v) : "memory");
}

// ---- converters ----
__global__ void k_conv_x(const float* __restrict__ x, unsigned short* __restrict__ xb, int n4){
  int i = blockIdx.x*blockDim.x + threadIdx.x;
  if (i >= n4) return;
  float4 v = ((const float4*)x)[i];
  u16x4 o = { f2bf(v.x), f2bf(v.y), f2bf(v.z), f2bf(v.w) };
  *(u16x4*)(xb + (size_t)i*4) = o;
}

__global__ void k_conv_w(const float* __restrict__ Wf, const float* __restrict__ Wi,
                         const float* __restrict__ Wg, const float* __restrict__ Wo,
                         unsigned short* __restrict__ Wxb, unsigned short* __restrict__ Whb){
  int i = blockIdx.x*blockDim.x + threadIdx.x;
  if (i >= 3072*192) return;
  int gj = i / 192; int kc = (i % 192)*4;
  int g = gj / 768, j = gj % 768;
  const float* W = (g==0)?Wf:(g==1)?Wi:(g==2)?Wg:Wo;
  float4 vx = *(const float4*)(W + (size_t)j*1536 + kc);
  float4 vh = *(const float4*)(W + (size_t)j*1536 + 768 + kc);
  u16x4 ox = {f2bf(vx.x),f2bf(vx.y),f2bf(vx.z),f2bf(vx.w)};
  u16x4 oh = {f2bf(vh.x),f2bf(vh.y),f2bf(vh.z),f2bf(vh.w)};
  *(u16x4*)(Wxb + (size_t)gj*768 + kc) = ox;
  *(u16x4*)(Whb + (size_t)gj*768 + kc) = oh;
}

__global__ void k_conv_b(const float* __restrict__ b0, const float* __restrict__ b1,
                         const float* __restrict__ b2, const float* __restrict__ b3,
                         float* __restrict__ ball){
  int i = blockIdx.x*blockDim.x + threadIdx.x;
  if (i >= 3072) return;
  int g = i/768, j = i%768;
  const float* b = (g==0)?b0:(g==1)?b1:(g==2)?b2:b3;
  ball[i] = b[j];
}

// ---- phase 1: Xg[t][gj][b] = (x @ Wx^T), bf16, no bias ----
__global__ __launch_bounds__(256) void k_gemm_x(const unsigned short* __restrict__ xb,
        const unsigned short* __restrict__ Wxb, unsigned short* __restrict__ Xg){
  __shared__ __align__(16) short Ald[128*32];
  __shared__ __align__(16) short Bld[128*32];
  int blk = blockIdx.x;
  int bm = blk / 24, bn = blk % 24;     // consecutive blocks share A-panel (L2)
  size_t Mbase = (size_t)bm*128; int Nbase = bn*128;
  int tid = threadIdx.x; int w = tid>>6, l = tid&63;
  int wm = w&1, wn = w>>1, lr = l&15, lg = l>>4;
  f32x4 acc[4][4];
  #pragma unroll
  for (int a=0;a<4;++a)
    #pragma unroll
    for(int b2=0;b2<4;++b2) acc[a][b2] = (f32x4){0.f,0.f,0.f,0.f};
  int c0i = tid, c1i = tid+256;
  int r0 = c0i>>2, o0 = (c0i&3)*8;
  int r1 = c1i>>2, o1 = (c1i&3)*8;
  for (int kt=0; kt<24; ++kt) {
    int k0 = kt*32;
    short8 a0 = *(const short8*)(xb + (Mbase + r0)*768 + k0 + o0);
    short8 a1 = *(const short8*)(xb + (Mbase + r1)*768 + k0 + o1);
    short8 b0 = *(const short8*)(Wxb + (size_t)(Nbase + r0)*768 + k0 + o0);
    short8 b1 = *(const short8*)(Wxb + (size_t)(Nbase + r1)*768 + k0 + o1);
    __syncthreads();
    *(short8*)(Ald + r0*32 + o0) = a0;
    *(short8*)(Ald + r1*32 + o1) = a1;
    *(short8*)(Bld + r0*32 + o0) = b0;
    *(short8*)(Bld + r1*32 + o1) = b1;
    __syncthreads();
    short8 af[4], bfr[4];
    #pragma unroll
    for (int mi=0;mi<4;++mi) af[mi] = *(const short8*)(Ald + (wm*64+mi*16+lr)*32 + lg*8);
    #pragma unroll
    for (int ni=0;ni<4;++ni) bfr[ni] = *(const short8*)(Bld + (wn*64+ni*16+lr)*32 + lg*8);
    #pragma unroll
    for (int mi=0;mi<4;++mi)
      #pragma unroll
      for (int ni=0;ni<4;++ni)
        acc[mi][ni] = mfma16(af[mi], bfr[ni], acc[mi][ni]);
  }
  #pragma unroll
  for (int mi=0;mi<4;++mi){
    int m0 = (int)Mbase + wm*64 + mi*16 + lg*4;
    int t = m0>>6, b = m0&63;
    #pragma unroll
    for (int ni=0;ni<4;++ni){
      int col = Nbase + wn*64 + ni*16 + lr;
      u16x4 u = { f2bf(acc[mi][ni][0]), f2bf(acc[mi][ni][1]),
                  f2bf(acc[mi][ni][2]), f2bf(acc[mi][ni][3]) };
      *(u16x4*)(Xg + ((size_t)t*3072 + col)*64 + b) = u;
    }
  }
}

// ---- phase 2: persistent recurrent kernel. 96 WGs x 512 threads (8 waves).
// h is stored per-timestep (hbase + t*HSTRIDE): addresses are never reused,
// so consumer loads are PLAIN cached loads (L1/L2 amplify the all-to-all;
// each XCD fetches h once from IF$, ~12 WGs share it). Producers store via
// sc0|sc1 bypass + own-wave vmcnt drain + per-t relaxed agent flag.
// Flags are also per-t (no reuse, no replay staleness). No cache-wide fences.
__global__ __launch_bounds__(512, 1) void k_lstm(const unsigned short* __restrict__ Xg,
     const unsigned short* __restrict__ Whb, const float* __restrict__ ball,
     unsigned short* __restrict__ hbase, float* __restrict__ out, int* __restrict__ flags){
  __shared__ __align__(16) short Wl[32*776];          // Wh slice (2-way aliasing only)
  __shared__ __align__(16) unsigned short hl[64*8];   // h pack tile
  int s = blockIdx.x, tid = threadIdx.x;
  int w8 = tid>>6, l = tid&63;
  int m = w8 & 3, nh = w8 >> 2;
  int n0 = l & 15, lg = l >> 4;
  int gate = n0 >> 2;
  int jj4 = nh*4 + (n0 & 3);           // 0..7 within this WG's j-slice
  int j = s*8 + jj4;
  size_t gj = (size_t)gate*768 + j;
  int rB = jj4*4 + gate;               // LDS row: gates interleaved

  // stage Wh slice once: Wl[rB][k] = Whb[gate*768 + s*8 + jj][k]
  for (int c = tid; c < 3072; c += 512){
    int r = c/96, off = (c%96)*8;
    int gt = r & 3, jq = r >> 2;
    short8 v = *(const short8*)(Whb + ((size_t)(gt*768 + s*8 + jq))*768 + off);
    *(short8*)(Wl + r*776 + off) = v;
  }
  __syncthreads();

  float bias = ball[gj];
  float cst[4] = {0.f, 0.f, 0.f, 0.f};
  int arow = m*16 + n0;
  int b4 = m*16 + lg*4;
  bool actv = (n0 < 4);
  u16x4 xg = *(const u16x4*)(Xg + gj*64 + b4);   // t=0 prefetch

  for (int t=0; t<512; ++t){
    const unsigned short* hb = hbase + (size_t)t*HSTRIDE;
    unsigned short* hn = hbase + (size_t)(t+1)*HSTRIDE;
    // A-fragments (h_t): plain cached 16B loads (fresh per-t address ->
    // no staleness possible; L1/L2 serve the intra-XCD re-reads)
    short8 afr[24];
    #pragma unroll
    for (int kk=0; kk<24; ++kk)
      afr[kk] = *(const short8*)(hb + arow*768 + kk*32 + lg*8);
    // MFMA with B streamed from LDS; two acc chains for latency
    f32x4 acc0 = {0.f,0.f,0.f,0.f}, acc1 = {0.f,0.f,0.f,0.f};
    #pragma unroll
    for (int kk=0; kk<24; kk+=2){
      short8 b0 = *(const short8*)(Wl + rB*776 + kk*32 + lg*8);
      short8 b1 = *(const short8*)(Wl + rB*776 + (kk+1)*32 + lg*8);
      acc0 = mfma16(afr[kk],   b0, acc0);
      acc1 = mfma16(afr[kk+1], b1, acc1);
    }
    f32x4 acc = acc0 + acc1;
    // pre-activation + this lane's gate nonlinearity (gate==2 -> tanh)
    float av[4];
    #pragma unroll
    for (int r=0; r<4; ++r){
      float pre = acc[r] + bf2f(xg[r]) + bias;
      av[r] = (gate == 2) ? tanh_s(pre) : sigm(pre);
    }
    // gather i (xor4), g (xor8), o (xor12); f is lane-local for n0<4
    float hvv[4];
    #pragma unroll
    for (int r=0; r<4; ++r){
      float iv = __shfl_xor(av[r], 4);
      float gv = __shfl_xor(av[r], 8);
      float ov = __shfl_xor(av[r], 12);
      float cn = av[r]*cst[r] + iv*gv;
      float hv = ov * tanh_s(cn);
      if (actv){
        cst[r] = cn;
        hvv[r] = hv;
        if (t < 511) hl[(b4 + r)*8 + jj4] = f2bf(hv);  // pack tile
      }
    }
    if (t < 511){
      __syncthreads();                   // hl complete
      if (w8 == 7){
        // 64 coalesced 16B h-stores to hbuf[t+1]; only these gate the flag
        short8 hp = *(const short8*)(hl + l*8);
        st_b128_sc(hn + (size_t)l*768 + s*8, hp);
        asm volatile("s_waitcnt vmcnt(0)" ::: "memory");
        if (l == 0)
          __hip_atomic_store(&flags[(size_t)t*FSTRIDE + s*16], 1,
                             __ATOMIC_RELAXED, __HIP_MEMORY_SCOPE_AGENT);
      }
      // out stores don't gate the flag (wave7 issues them post-flag)
      if (actv){
        #pragma unroll
        for (int r=0; r<4; ++r)
          out[((size_t)t*64 + b4 + r)*768 + j] = hvv[r];
      }
      u16x4 xgn = *(const u16x4*)(Xg + ((size_t)(t+1)*3072 + gj)*64 + b4);
      if (w8 == 0){
        const int* fl = flags + (size_t)t*FSTRIDE;
        // bounded spin, wave 0 only; poll loads bypass L2 (sc1) via atomic
        for (int it=0; it<(1<<14); ++it){
          int f1 = __hip_atomic_load(&fl[l*16], __ATOMIC_RELAXED, __HIP_MEMORY_SCOPE_AGENT);
          int f2 = (l<32) ? __hip_atomic_load(&fl[(64+l)*16], __ATOMIC_RELAXED, __HIP_MEMORY_SCOPE_AGENT) : 1;
          if (__all(f1!=0 && f2!=0)) break;
          __builtin_amdgcn_s_sleep(1);
        }
      }
      __syncthreads();                   // release: all 96 flags set for t
      xg = xgn;
    } else if (actv){
      #pragma unroll
      for (int r=0; r<4; ++r){
        int b = b4 + r;
        out[((size_t)t*64 + b)*768 + j] = hvv[r];
        out[(512UL*64 + b)*768 + j] = hvv[r];        // hT
        out[(512UL*64 + 64 + b)*768 + j] = cst[r];   // cT
      }
    }
  }
}

extern "C" void kernel_launch(void* const* d_in, const int* in_sizes, int n_in,
                              void* d_out, int out_size, void* d_ws, size_t ws_size,
                              hipStream_t stream){
  const float* x   = (const float*)d_in[0];
  const float* Wf  = (const float*)d_in[1];
  const float* bf_ = (const float*)d_in[2];
  const float* Wi  = (const float*)d_in[3];
  const float* bi_ = (const float*)d_in[4];
  const float* Wg  = (const float*)d_in[5];
  const float* bg_ = (const float*)d_in[6];
  const float* Wo  = (const float*)d_in[7];
  const float* bo_ = (const float*)d_in[8];
  char* ws = (char*)d_ws;
  if (ws_size < OFF_END) return;  // need ~252 MB scratch
  unsigned short* xb   = (unsigned short*)(ws + OFF_XBF);   // then: per-t h buffers
  unsigned short* Wxb  = (unsigned short*)(ws + OFF_WXB);   // then: per-t flags
  unsigned short* Whb  = (unsigned short*)(ws + OFF_WHB);
  float*          ball = (float*)(ws + OFF_BALL);
  unsigned short* Xg   = (unsigned short*)(ws + OFF_XG);
  float* out = (float*)d_out;

  k_conv_x<<<24576, 256, 0, stream>>>(x, xb, 6291456);
  k_conv_w<<<2304, 256, 0, stream>>>(Wf, Wi, Wg, Wo, Wxb, Whb);
  k_conv_b<<<12, 256, 0, stream>>>(bf_, bi_, bg_, bo_, ball);
  k_gemm_x<<<6144, 256, 0, stream>>>(xb, Wxb, Xg);
  // xb/Wxb are dead now; reuse as per-t h buffers (h0=0) and per-t flags=0.
  // (MUST be after k_gemm_x in stream order; reset every call for replays.)
  (void)hipMemsetAsync(ws + OFF_XBF, 0, 98304, stream);            // h[0] = 0
  (void)hipMemsetAsync(ws + OFF_WXB, 0, 512UL*FSTRIDE*4, stream);  // flags = 0
  k_lstm<<<NWG, 512, 0, stream>>>(Xg, Whb, ball,
                                  (unsigned short*)(ws + OFF_XBF), out,
                                  (int*)(ws + OFF_WXB));
}